// Round 5
// baseline (188.978 us; speedup 1.0000x reference)
//
#include <hip/hip_runtime.h>
#include <cstdint>

#define IN_DIM 2048   // 2H
#define H_DIM  1024
#define BROWS  2048   // B*R
#define BATCH  64
#define ROUNDS 32

typedef __bf16 bf16x8 __attribute__((ext_vector_type(8)));
typedef float  f32x4  __attribute__((ext_vector_type(4)));
typedef unsigned short u16;

// fp32 -> bf16 (RNE)
__device__ __forceinline__ u16 f2bf(float f) {
    unsigned int u = __float_as_uint(f);
    u += 0x7FFFu + ((u >> 16) & 1u);
    return (u16)(u >> 16);
}

// async global->LDS, 16 bytes/lane. LDS dest is wave-uniform base; HW adds lane*16.
__device__ __forceinline__ void async_ld16(const void* g, void* l) {
    __builtin_amdgcn_global_load_lds(
        (__attribute__((address_space(1))) void*)(uintptr_t)g,
        (__attribute__((address_space(3))) void*)(unsigned int)(uintptr_t)l,
        16, 0, 0);
}

// ---------------- 1. prep: input bf16 convert + fused weight transpose (merged launch) -------
__global__ __launch_bounds__(256) void prep(
    const float* __restrict__ hist, const float* __restrict__ ques,
    u16* __restrict__ xh, u16* __restrict__ xq,
    const float* __restrict__ why, const float* __restrict__ whg,
    const float* __restrict__ wqy, const float* __restrict__ wqg,
    u16* __restrict__ oh, u16* __restrict__ oq)
{
    int idx = blockIdx.x;
    if (idx < 4096) {
        int i = idx * 256 + threadIdx.x;
        const float4* h4 = (const float4*)hist;
        const float4* q4 = (const float4*)ques;
        float4 a = h4[i], b = q4[i];
        ushort4 oa, ob;
        oa.x = f2bf(a.x); oa.y = f2bf(a.y); oa.z = f2bf(a.z); oa.w = f2bf(a.w);
        ob.x = f2bf(b.x); ob.y = f2bf(b.y); ob.z = f2bf(b.z); ob.w = f2bf(b.w);
        ((ushort4*)xh)[i] = oa;
        ((ushort4*)xq)[i] = ob;
        return;
    }
    __shared__ float t[32][33];
    int zz = idx - 4096;
    int z = zz >> 12, rem = zz & 4095;
    const float* Y = z == 0 ? why : wqy;
    const float* G = z == 0 ? whg : wqg;
    u16* O = z == 0 ? oh : oq;
    int n0 = (rem & 63) * 32, k0 = (rem >> 6) * 32;
    int tx = threadIdx.x & 31, ty = threadIdx.x >> 5;   // 32 x 8
    const float* S = (tx < 16) ? Y : G;
    int sc = (n0 >> 1) + (tx & 15);
    #pragma unroll
    for (int r = 0; r < 4; r++)
        t[ty + 8*r][tx] = S[(size_t)(k0 + ty + 8*r) * H_DIM + sc];
    __syncthreads();
    #pragma unroll
    for (int r = 0; r < 4; r++)
        O[(size_t)(n0 + ty + 8*r) * IN_DIM + k0 + tx] = f2bf(t[tx][ty + 8*r]);
}

// ---------------- 2. bf16 MFMA GEMM, BK=64 double-buffered LDS (loads overlap compute) -------
// A[2048,2048]bf16 @ Wt[2048(N),2048(K)]bf16 -> E[2048,1024] bf16 (tanh*leaky fused).
// Pipeline: barrier -> issue async loads for tile t+1 into other buffer -> MFMA tile t.
// The vmcnt(0) drain before the NEXT barrier waits on loads that had a full compute
// phase in flight (vs R4 where staging was issued right before its own drain).
__global__ __launch_bounds__(256) void gemm_act(
    const u16* __restrict__ xh, const u16* __restrict__ xq,
    const u16* __restrict__ wth, const u16* __restrict__ wtq,
    const float* __restrict__ bhy, const float* __restrict__ bhg,
    const float* __restrict__ bqy, const float* __restrict__ bqg,
    u16* __restrict__ eh, u16* __restrict__ eq)
{
    int z = blockIdx.z;
    const u16* A  = z == 0 ? xh : xq;
    const u16* Bt = z == 0 ? wth : wtq;
    const float* by = z == 0 ? bhy : bqy;
    const float* bg = z == 0 ? bhg : bqg;
    u16* E = z == 0 ? eh : eq;

    // 2 x (16 KB A + 16 KB B) = 64 KB; 128 rows x 8 chunks of 16B; phys chunk = kc ^ (row&7)
    __shared__ __align__(16) u16 As[2][128 * 64];
    __shared__ __align__(16) u16 Bs[2][128 * 64];

    int tid = threadIdx.x;
    int wave = tid >> 6, lane = tid & 63;
    int lane15 = lane & 15, quad = lane >> 4;
    int wm = (wave >> 1) * 64, wn = (wave & 1) * 64;
    int m0 = blockIdx.y * 128, n0 = blockIdx.x * 128;

    f32x4 acc[4][4];
    #pragma unroll
    for (int i = 0; i < 4; i++)
        #pragma unroll
        for (int j = 0; j < 4; j++) acc[i][j] = (f32x4){0.f, 0.f, 0.f, 0.f};

    // 4 staging slots per matrix (1024 chunks / 256 threads)
    int srow[4], skc[4], scb[4];
    #pragma unroll
    for (int r2 = 0; r2 < 4; r2++) {
        int cbase = r2 * 256 + wave * 64;     // wave-uniform chunk base
        int cs = cbase + lane;
        int row = cs >> 3, s = cs & 7;
        srow[r2] = row; skc[r2] = s ^ (row & 7); scb[r2] = cbase;
    }

    #define STAGE(buf, kt)                                                                   \
        _Pragma("unroll")                                                                    \
        for (int r2 = 0; r2 < 4; r2++) {                                                     \
            async_ld16(A  + (size_t)(m0 + srow[r2]) * IN_DIM + (kt) + skc[r2] * 8,           \
                       &As[buf][scb[r2] * 8]);                                               \
            async_ld16(Bt + (size_t)(n0 + srow[r2]) * IN_DIM + (kt) + skc[r2] * 8,           \
                       &Bs[buf][scb[r2] * 8]);                                               \
        }

    #define COMPUTE(buf)                                                                     \
        _Pragma("unroll")                                                                    \
        for (int ks = 0; ks < 2; ks++) {                                                     \
            bf16x8 af[4], bfv[4];                                                            \
            _Pragma("unroll")                                                                \
            for (int i = 0; i < 4; i++) {                                                    \
                int row = wm + i * 16 + lane15;                                              \
                int s = (ks * 4 + quad) ^ (row & 7);                                         \
                af[i] = *(const bf16x8*)&As[buf][row * 64 + s * 8];                          \
            }                                                                                \
            _Pragma("unroll")                                                                \
            for (int j = 0; j < 4; j++) {                                                    \
                int row = wn + j * 16 + lane15;                                              \
                int s = (ks * 4 + quad) ^ (row & 7);                                         \
                bfv[j] = *(const bf16x8*)&Bs[buf][row * 64 + s * 8];                         \
            }                                                                                \
            _Pragma("unroll")                                                                \
            for (int i = 0; i < 4; i++)                                                      \
                _Pragma("unroll")                                                            \
                for (int j = 0; j < 4; j++)                                                  \
                    acc[i][j] = __builtin_amdgcn_mfma_f32_16x16x32_bf16(                     \
                        af[i], bfv[j], acc[i][j], 0, 0, 0);                                  \
        }

    STAGE(0, 0)
    for (int kt = 0; kt < IN_DIM; kt += 128) {
        __syncthreads();                       // drains buf0 loads (issued last phase)
        STAGE(1, kt + 64)                      // prefetch next half-tile while computing
        COMPUTE(0)
        __syncthreads();                       // drains buf1 loads
        if (kt + 128 < IN_DIM) STAGE(0, kt + 128)
        COMPUTE(1)
    }
    #undef STAGE
    #undef COMPUTE

    // epilogue: j-pairs (0,1),(2,3) = (tanh, gate) branches of the same H-col, same lane.
    int n0w = n0 + wn;
    #pragma unroll
    for (int jp = 0; jp < 2; jp++) {
        int hc = (n0w >> 1) + jp * 16 + lane15;
        float vy = by[hc], vg = bg[hc];
        #pragma unroll
        for (int i = 0; i < 4; i++) {
            #pragma unroll
            for (int r = 0; r < 4; r++) {
                int row = m0 + wm + i * 16 + quad * 4 + r;
                float y = tanhf(acc[i][2 * jp][r] + vy);
                float g = acc[i][2 * jp + 1][r] + vg;
                E[(size_t)row * H_DIM + hc] = f2bf(y * (g > 0.f ? g : 0.01f * g));
            }
        }
    }
}

// ---------------- 3. scores + causal softmax + weighted hist sum (bf16 E) ----------------
// Linear grid idx = q*64 + b  =>  XCD = b%8: all q-blocks of a batch share one XCD L2.
__global__ __launch_bounds__(256) void score_feat(
    const u16* __restrict__ eh, const u16* __restrict__ eq,
    const float* __restrict__ hist, const float* __restrict__ watt,
    const float* __restrict__ batt, float* __restrict__ out)
{
    int idx = blockIdx.x;
    int b = idx & 63, q = idx >> 6;
    int tid = threadIdx.x, wave = tid >> 6, lane = tid & 63;
    __shared__ float sw[32], swn[32];

    const u16* qe = eq + (size_t)(b * ROUNDS + q) * H_DIM;
    float uw[16], u2[16];
    #pragma unroll
    for (int c = 0; c < 2; c++) {
        uint4 pk = ((const uint4*)qe)[lane + 64 * c];     // 8 bf16
        float4 w0 = ((const float4*)watt)[(lane + 64 * c) * 2];
        float4 w1 = ((const float4*)watt)[(lane + 64 * c) * 2 + 1];
        unsigned int ws[4] = {pk.x, pk.y, pk.z, pk.w};
        float wf[8] = {w0.x, w0.y, w0.z, w0.w, w1.x, w1.y, w1.z, w1.w};
        #pragma unroll
        for (int e = 0; e < 4; e++) {
            float lo = __uint_as_float(ws[e] << 16);
            float hi = __uint_as_float(ws[e] & 0xFFFF0000u);
            uw[c * 8 + 2 * e]     = lo * wf[2 * e];
            u2[c * 8 + 2 * e]     = lo * lo;
            uw[c * 8 + 2 * e + 1] = hi * wf[2 * e + 1];
            u2[c * 8 + 2 * e + 1] = hi * hi;
        }
    }
    for (int h = wave; h <= q; h += 4) {
        const u16* he = eh + (size_t)(b * ROUNDS + h) * H_DIM;
        float num = 0.f, nrm = 0.f;
        #pragma unroll
        for (int c = 0; c < 2; c++) {
            uint4 pk = ((const uint4*)he)[lane + 64 * c];
            unsigned int vs[4] = {pk.x, pk.y, pk.z, pk.w};
            #pragma unroll
            for (int e = 0; e < 4; e++) {
                float lo = __uint_as_float(vs[e] << 16);
                float hi = __uint_as_float(vs[e] & 0xFFFF0000u);
                num += uw[c * 8 + 2 * e] * lo + uw[c * 8 + 2 * e + 1] * hi;
                nrm += u2[c * 8 + 2 * e] * lo * lo + u2[c * 8 + 2 * e + 1] * hi * hi;
            }
        }
        #pragma unroll
        for (int off = 32; off > 0; off >>= 1) {
            num += __shfl_down(num, off);
            nrm += __shfl_down(nrm, off);
        }
        if (lane == 0)
            sw[h] = num / fmaxf(sqrtf(nrm), 1e-12f) + batt[0];
    }
    __syncthreads();
    if (tid == 0) {
        float mx = -1e30f;
        for (int h = 0; h <= q; h++) mx = fmaxf(mx, sw[h]);
        float zs = 0.f;
        for (int h = 0; h <= q; h++) { float e = expf(sw[h] - mx); swn[h] = e; zs += e; }
        float inv = 1.f / zs;
        for (int h = 0; h <= q; h++) swn[h] *= inv;
    }
    __syncthreads();
    const float4* hb = (const float4*)(hist + (size_t)b * ROUNDS * IN_DIM);
    float4* ob = (float4*)(out + (size_t)(b * ROUNDS + q) * IN_DIM);
    #pragma unroll
    for (int d0 = 0; d0 < 2; d0++) {
        int d = tid + d0 * 256;          // < 512 float4s
        float4 a = {0.f, 0.f, 0.f, 0.f};
        for (int h = 0; h <= q; h++) {
            float w = swn[h];
            float4 x = hb[h * 512 + d];
            a.x += w * x.x; a.y += w * x.y; a.z += w * x.z; a.w += w * x.w;
        }
        ob[d] = a;
    }
}

extern "C" void kernel_launch(void* const* d_in, const int* in_sizes, int n_in,
                              void* d_out, int out_size, void* d_ws, size_t ws_size,
                              hipStream_t stream) {
    const float* hist = (const float*)d_in[0];
    const float* ques = (const float*)d_in[1];
    const float* Why  = (const float*)d_in[2];
    const float* bhy  = (const float*)d_in[3];
    const float* Whg  = (const float*)d_in[4];
    const float* bhg  = (const float*)d_in[5];
    const float* Wqy  = (const float*)d_in[6];
    const float* bqy  = (const float*)d_in[7];
    const float* Wqg  = (const float*)d_in[8];
    const float* bqg  = (const float*)d_in[9];
    const float* watt = (const float*)d_in[10];
    const float* batt = (const float*)d_in[11];
    float* out = (float*)d_out;

    // workspace (~42 MB)
    char* w = (char*)d_ws;
    u16* Xh  = (u16*)w;                               // [2048,2048] bf16
    u16* Xq  = Xh  + (size_t)BROWS * IN_DIM;
    u16* WtH = Xq  + (size_t)BROWS * IN_DIM;          // [2048,2048] bf16 fused-interleaved
    u16* WtQ = WtH + (size_t)IN_DIM * IN_DIM;
    u16* Eh  = WtQ + (size_t)IN_DIM * IN_DIM;         // [2048,1024] bf16
    u16* Eq  = Eh  + (size_t)BROWS * H_DIM;

    prep<<<12288, 256, 0, stream>>>(hist, ques, Xh, Xq, Why, Whg, Wqy, Wqg, WtH, WtQ);
    gemm_act<<<dim3(16, 16, 2), 256, 0, stream>>>(Xh, Xq, WtH, WtQ,
                                                  bhy, bhg, bqy, bqg, Eh, Eq);
    score_feat<<<2048, 256, 0, stream>>>(Eh, Eq, hist, watt, batt, out);
}

// Round 6
// 183.220 us; speedup vs baseline: 1.0314x; 1.0314x over previous
//
#include <hip/hip_runtime.h>
#include <cstdint>

#define IN_DIM 2048   // 2H
#define H_DIM  1024
#define BROWS  2048   // B*R
#define BATCH  64
#define ROUNDS 32

typedef __bf16 bf16x8 __attribute__((ext_vector_type(8)));
typedef float  f32x4  __attribute__((ext_vector_type(4)));
typedef unsigned short u16;

// fp32 -> bf16 (RNE)
__device__ __forceinline__ u16 f2bf(float f) {
    unsigned int u = __float_as_uint(f);
    u += 0x7FFFu + ((u >> 16) & 1u);
    return (u16)(u >> 16);
}

// async global->LDS, 16 bytes/lane. LDS dest is wave-uniform base; HW adds lane*16.
__device__ __forceinline__ void async_ld16(const void* g, void* l) {
    __builtin_amdgcn_global_load_lds(
        (__attribute__((address_space(1))) void*)(uintptr_t)g,
        (__attribute__((address_space(3))) void*)(unsigned int)(uintptr_t)l,
        16, 0, 0);
}

// ---------------- 1. prep: input bf16 convert + fused weight transpose (merged launch) -------
__global__ __launch_bounds__(256) void prep(
    const float* __restrict__ hist, const float* __restrict__ ques,
    u16* __restrict__ xh, u16* __restrict__ xq,
    const float* __restrict__ why, const float* __restrict__ whg,
    const float* __restrict__ wqy, const float* __restrict__ wqg,
    u16* __restrict__ oh, u16* __restrict__ oq)
{
    int idx = blockIdx.x;
    if (idx < 4096) {
        int i = idx * 256 + threadIdx.x;
        const float4* h4 = (const float4*)hist;
        const float4* q4 = (const float4*)ques;
        float4 a = h4[i], b = q4[i];
        ushort4 oa, ob;
        oa.x = f2bf(a.x); oa.y = f2bf(a.y); oa.z = f2bf(a.z); oa.w = f2bf(a.w);
        ob.x = f2bf(b.x); ob.y = f2bf(b.y); ob.z = f2bf(b.z); ob.w = f2bf(b.w);
        ((ushort4*)xh)[i] = oa;
        ((ushort4*)xq)[i] = ob;
        return;
    }
    __shared__ float t[32][33];
    int zz = idx - 4096;
    int z = zz >> 12, rem = zz & 4095;
    const float* Y = z == 0 ? why : wqy;
    const float* G = z == 0 ? whg : wqg;
    u16* O = z == 0 ? oh : oq;
    int n0 = (rem & 63) * 32, k0 = (rem >> 6) * 32;
    int tx = threadIdx.x & 31, ty = threadIdx.x >> 5;   // 32 x 8
    const float* S = (tx < 16) ? Y : G;
    int sc = (n0 >> 1) + (tx & 15);
    #pragma unroll
    for (int r = 0; r < 4; r++)
        t[ty + 8*r][tx] = S[(size_t)(k0 + ty + 8*r) * H_DIM + sc];
    __syncthreads();
    #pragma unroll
    for (int r = 0; r < 4; r++)
        O[(size_t)(n0 + ty + 8*r) * IN_DIM + k0 + tx] = f2bf(t[tx][ty + 8*r]);
}

// ---------------- 2. bf16 MFMA GEMM, BK=64 dbuf, XCD-clustered grid ----------------
// 1D grid of 512 blocks. XCD = id%8 (dispatch heuristic). Cluster c = 8y x 8x blocks of one z
// pinned to XCD c: per-XCD concurrent footprint 4 MB A-rows + 4 MB B-rows (vs 18 MB unswizzled)
// -> staging loads mostly L2-hit -> shorter vmcnt drains at each barrier.
__global__ __launch_bounds__(256) void gemm_act(
    const u16* __restrict__ xh, const u16* __restrict__ xq,
    const u16* __restrict__ wth, const u16* __restrict__ wtq,
    const float* __restrict__ bhy, const float* __restrict__ bhg,
    const float* __restrict__ bqy, const float* __restrict__ bqg,
    u16* __restrict__ eh, u16* __restrict__ eq)
{
    int L = blockIdx.x;
    int cluster = L & 7;          // -> XCD via id%8
    int slot = L >> 3;            // 0..63 within cluster
    int z  = cluster >> 2;
    int y  = (cluster & 1) * 8 + (slot >> 3);
    int x  = ((cluster >> 1) & 1) * 8 + (slot & 7);
    int m0 = y * 128, n0 = x * 128;

    const u16* A  = z == 0 ? xh : xq;
    const u16* Bt = z == 0 ? wth : wtq;
    const float* by = z == 0 ? bhy : bqy;
    const float* bg = z == 0 ? bhg : bqg;
    u16* E = z == 0 ? eh : eq;

    // 2 x (16 KB A + 16 KB B) = 64 KB; 128 rows x 8 chunks of 16B; phys chunk = kc ^ (row&7)
    __shared__ __align__(16) u16 As[2][128 * 64];
    __shared__ __align__(16) u16 Bs[2][128 * 64];

    int tid = threadIdx.x;
    int wave = tid >> 6, lane = tid & 63;
    int lane15 = lane & 15, quad = lane >> 4;
    int wm = (wave >> 1) * 64, wn = (wave & 1) * 64;

    f32x4 acc[4][4];
    #pragma unroll
    for (int i = 0; i < 4; i++)
        #pragma unroll
        for (int j = 0; j < 4; j++) acc[i][j] = (f32x4){0.f, 0.f, 0.f, 0.f};

    // 4 staging slots per matrix (1024 chunks / 256 threads)
    int srow[4], skc[4], scb[4];
    #pragma unroll
    for (int r2 = 0; r2 < 4; r2++) {
        int cbase = r2 * 256 + wave * 64;     // wave-uniform chunk base
        int cs = cbase + lane;
        int row = cs >> 3, s = cs & 7;
        srow[r2] = row; skc[r2] = s ^ (row & 7); scb[r2] = cbase;
    }

    #define STAGE(buf, kt)                                                                   \
        _Pragma("unroll")                                                                    \
        for (int r2 = 0; r2 < 4; r2++) {                                                     \
            async_ld16(A  + (size_t)(m0 + srow[r2]) * IN_DIM + (kt) + skc[r2] * 8,           \
                       &As[buf][scb[r2] * 8]);                                               \
            async_ld16(Bt + (size_t)(n0 + srow[r2]) * IN_DIM + (kt) + skc[r2] * 8,           \
                       &Bs[buf][scb[r2] * 8]);                                               \
        }

    #define COMPUTE(buf)                                                                     \
        _Pragma("unroll")                                                                    \
        for (int ks = 0; ks < 2; ks++) {                                                     \
            bf16x8 af[4], bfv[4];                                                            \
            _Pragma("unroll")                                                                \
            for (int i = 0; i < 4; i++) {                                                    \
                int row = wm + i * 16 + lane15;                                              \
                int s = (ks * 4 + quad) ^ (row & 7);                                         \
                af[i] = *(const bf16x8*)&As[buf][row * 64 + s * 8];                          \
            }                                                                                \
            _Pragma("unroll")                                                                \
            for (int j = 0; j < 4; j++) {                                                    \
                int row = wn + j * 16 + lane15;                                              \
                int s = (ks * 4 + quad) ^ (row & 7);                                         \
                bfv[j] = *(const bf16x8*)&Bs[buf][row * 64 + s * 8];                         \
            }                                                                                \
            _Pragma("unroll")                                                                \
            for (int i = 0; i < 4; i++)                                                      \
                _Pragma("unroll")                                                            \
                for (int j = 0; j < 4; j++)                                                  \
                    acc[i][j] = __builtin_amdgcn_mfma_f32_16x16x32_bf16(                     \
                        af[i], bfv[j], acc[i][j], 0, 0, 0);                                  \
        }

    STAGE(0, 0)
    for (int kt = 0; kt < IN_DIM; kt += 128) {
        __syncthreads();                       // drains buf0 loads (issued last phase)
        STAGE(1, kt + 64)                      // prefetch next half-tile while computing
        COMPUTE(0)
        __syncthreads();                       // drains buf1 loads
        if (kt + 128 < IN_DIM) STAGE(0, kt + 128)
        COMPUTE(1)
    }
    #undef STAGE
    #undef COMPUTE

    // epilogue: j-pairs (0,1),(2,3) = (tanh, gate) branches of the same H-col, same lane.
    int n0w = n0 + wn;
    #pragma unroll
    for (int jp = 0; jp < 2; jp++) {
        int hc = (n0w >> 1) + jp * 16 + lane15;
        float vy = by[hc], vg = bg[hc];
        #pragma unroll
        for (int i = 0; i < 4; i++) {
            #pragma unroll
            for (int r = 0; r < 4; r++) {
                int row = m0 + wm + i * 16 + quad * 4 + r;
                float y2 = tanhf(acc[i][2 * jp][r] + vy);
                float g = acc[i][2 * jp + 1][r] + vg;
                E[(size_t)row * H_DIM + hc] = f2bf(y2 * (g > 0.f ? g : 0.01f * g));
            }
        }
    }
}

// ---------------- 3. scores + causal softmax + weighted hist sum (bf16 E) ----------------
// Linear grid idx = q*64 + b  =>  XCD = b%8: all q-blocks of a batch share one XCD L2.
__global__ __launch_bounds__(256) void score_feat(
    const u16* __restrict__ eh, const u16* __restrict__ eq,
    const float* __restrict__ hist, const float* __restrict__ watt,
    const float* __restrict__ batt, float* __restrict__ out)
{
    int idx = blockIdx.x;
    int b = idx & 63, q = idx >> 6;
    int tid = threadIdx.x, wave = tid >> 6, lane = tid & 63;
    __shared__ float sw[32], swn[32];

    const u16* qe = eq + (size_t)(b * ROUNDS + q) * H_DIM;
    float uw[16], u2[16];
    #pragma unroll
    for (int c = 0; c < 2; c++) {
        uint4 pk = ((const uint4*)qe)[lane + 64 * c];     // 8 bf16
        float4 w0 = ((const float4*)watt)[(lane + 64 * c) * 2];
        float4 w1 = ((const float4*)watt)[(lane + 64 * c) * 2 + 1];
        unsigned int ws[4] = {pk.x, pk.y, pk.z, pk.w};
        float wf[8] = {w0.x, w0.y, w0.z, w0.w, w1.x, w1.y, w1.z, w1.w};
        #pragma unroll
        for (int e = 0; e < 4; e++) {
            float lo = __uint_as_float(ws[e] << 16);
            float hi = __uint_as_float(ws[e] & 0xFFFF0000u);
            uw[c * 8 + 2 * e]     = lo * wf[2 * e];
            u2[c * 8 + 2 * e]     = lo * lo;
            uw[c * 8 + 2 * e + 1] = hi * wf[2 * e + 1];
            u2[c * 8 + 2 * e + 1] = hi * hi;
        }
    }
    for (int h = wave; h <= q; h += 4) {
        const u16* he = eh + (size_t)(b * ROUNDS + h) * H_DIM;
        float num = 0.f, nrm = 0.f;
        #pragma unroll
        for (int c = 0; c < 2; c++) {
            uint4 pk = ((const uint4*)he)[lane + 64 * c];
            unsigned int vs[4] = {pk.x, pk.y, pk.z, pk.w};
            #pragma unroll
            for (int e = 0; e < 4; e++) {
                float lo = __uint_as_float(vs[e] << 16);
                float hi = __uint_as_float(vs[e] & 0xFFFF0000u);
                num += uw[c * 8 + 2 * e] * lo + uw[c * 8 + 2 * e + 1] * hi;
                nrm += u2[c * 8 + 2 * e] * lo * lo + u2[c * 8 + 2 * e + 1] * hi * hi;
            }
        }
        #pragma unroll
        for (int off = 32; off > 0; off >>= 1) {
            num += __shfl_down(num, off);
            nrm += __shfl_down(nrm, off);
        }
        if (lane == 0)
            sw[h] = num / fmaxf(sqrtf(nrm), 1e-12f) + batt[0];
    }
    __syncthreads();
    if (tid == 0) {
        float mx = -1e30f;
        for (int h = 0; h <= q; h++) mx = fmaxf(mx, sw[h]);
        float zs = 0.f;
        for (int h = 0; h <= q; h++) { float e = expf(sw[h] - mx); swn[h] = e; zs += e; }
        float inv = 1.f / zs;
        for (int h = 0; h <= q; h++) swn[h] *= inv;
    }
    __syncthreads();
    const float4* hb = (const float4*)(hist + (size_t)b * ROUNDS * IN_DIM);
    float4* ob = (float4*)(out + (size_t)(b * ROUNDS + q) * IN_DIM);
    #pragma unroll
    for (int d0 = 0; d0 < 2; d0++) {
        int d = tid + d0 * 256;          // < 512 float4s
        float4 a = {0.f, 0.f, 0.f, 0.f};
        for (int h = 0; h <= q; h++) {
            float w = swn[h];
            float4 x = hb[h * 512 + d];
            a.x += w * x.x; a.y += w * x.y; a.z += w * x.z; a.w += w * x.w;
        }
        ob[d] = a;
    }
}

extern "C" void kernel_launch(void* const* d_in, const int* in_sizes, int n_in,
                              void* d_out, int out_size, void* d_ws, size_t ws_size,
                              hipStream_t stream) {
    const float* hist = (const float*)d_in[0];
    const float* ques = (const float*)d_in[1];
    const float* Why  = (const float*)d_in[2];
    const float* bhy  = (const float*)d_in[3];
    const float* Whg  = (const float*)d_in[4];
    const float* bhg  = (const float*)d_in[5];
    const float* Wqy  = (const float*)d_in[6];
    const float* bqy  = (const float*)d_in[7];
    const float* Wqg  = (const float*)d_in[8];
    const float* bqg  = (const float*)d_in[9];
    const float* watt = (const float*)d_in[10];
    const float* batt = (const float*)d_in[11];
    float* out = (float*)d_out;

    // workspace (~42 MB)
    char* w = (char*)d_ws;
    u16* Xh  = (u16*)w;                               // [2048,2048] bf16
    u16* Xq  = Xh  + (size_t)BROWS * IN_DIM;
    u16* WtH = Xq  + (size_t)BROWS * IN_DIM;          // [2048,2048] bf16 fused-interleaved
    u16* WtQ = WtH + (size_t)IN_DIM * IN_DIM;
    u16* Eh  = WtQ + (size_t)IN_DIM * IN_DIM;         // [2048,1024] bf16
    u16* Eq  = Eh  + (size_t)BROWS * H_DIM;

    prep<<<12288, 256, 0, stream>>>(hist, ques, Xh, Xq, Why, Whg, Wqy, Wqg, WtH, WtQ);
    gemm_act<<<512, 256, 0, stream>>>(Xh, Xq, WtH, WtQ, bhy, bhg, bqy, bqg, Eh, Eq);
    score_feat<<<2048, 256, 0, stream>>>(Eh, Eq, hist, watt, batt, out);
}